// Round 5
// baseline (254.083 us; speedup 1.0000x reference)
//
#include <hip/hip_runtime.h>

#define NPI    33600     // anchors per image: 160^2 + 80^2 + 40^2
#define KTOP   500
#define CAP    1024
#define KEY001 0xBC23D70Au   // monotonic key of 0.01f
#define NGRP   1024
#define NIMG   8
#define GPW    525       // uint4 groups per wave in phase B (NPI/4/16)

__device__ __forceinline__ float sigmoidf_(float x) {
  return 1.0f / (1.0f + expf(-x));
}
// monotonic float -> u32 key (order-preserving for all non-NaN floats)
__device__ __forceinline__ unsigned fkey(float f) {
  unsigned u = __float_as_uint(f);
  return (u & 0x80000000u) ? ~u : (u | 0x80000000u);
}
__device__ __forceinline__ unsigned long long rdlane64(unsigned long long v, int l) {
  unsigned lo = (unsigned)__builtin_amdgcn_readlane((int)(unsigned)(v & 0xFFFFFFFFull), l);
  unsigned hi = (unsigned)__builtin_amdgcn_readlane((int)(unsigned)(v >> 32), l);
  return ((unsigned long long)hi << 32) | lo;
}
__device__ __forceinline__ float rdlanef(float v, int l) {
  return __uint_as_float((unsigned)__builtin_amdgcn_readlane((int)__float_as_uint(v), l));
}

// ---------------- Kernel 1: streaming decode + keys + fused coarse hist ----------
// 2 anchors/thread, float2 reads, 8-deep batches; 528 blocks -> 8 waves/CU.
__global__ __launch_bounds__(256) void k_decode(
    const float* __restrict__ p8, const float* __restrict__ p16,
    const float* __restrict__ p32,
    unsigned* __restrict__ keys, float* __restrict__ dets,
    unsigned* __restrict__ hist2)
{
  const int b = blockIdx.y;
  const int t = blockIdx.x * 256 + threadIdx.x;
  const int a = t * 2;
  __shared__ unsigned lh[NGRP];
  for (int i = threadIdx.x; i < NGRP; i += 256) lh[i] = 0;
  __syncthreads();

  if (a < NPI) {
    const float* lvl; int j, W, HW, S;
    if (a < 25600)      { lvl = p8;  j = a;         W = 160; HW = 25600; S = 8;  }
    else if (a < 32000) { lvl = p16; j = a - 25600; W = 80;  HW = 6400;  S = 16; }
    else                { lvl = p32; j = a - 32000; W = 40;  HW = 1600;  S = 32; }
    const float* base = lvl + (size_t)b * 85 * HW + j;
    float2 t0 = *(const float2*)(base);
    float2 t1 = *(const float2*)(base + (size_t)1 * HW);
    float2 t2 = *(const float2*)(base + (size_t)2 * HW);
    float2 t3 = *(const float2*)(base + (size_t)3 * HW);
    float2 t4 = *(const float2*)(base + (size_t)4 * HW);
    // exact per-class sigmoid argmax, first occurrence (strict >)
    float cc[2] = {-1.0f, -1.0f};
    int   lab[2] = {0, 0};
    for (int c0 = 0; c0 < 80; c0 += 8) {
      float2 r[8];
      #pragma unroll
      for (int u = 0; u < 8; ++u)
        r[u] = *(const float2*)(base + (size_t)(5 + c0 + u) * HW);
      #pragma unroll
      for (int u = 0; u < 8; ++u) {
        float s;
        s = sigmoidf_(r[u].x); if (s > cc[0]) { cc[0] = s; lab[0] = c0 + u; }
        s = sigmoidf_(r[u].y); if (s > cc[1]) { cc[1] = s; lab[1] = c0 + u; }
      }
    }
    float e0[2] = {t0.x, t0.y};
    float e1[2] = {t1.x, t1.y};
    float e2[2] = {t2.x, t2.y};
    float e3[2] = {t3.x, t3.y};
    float e4[2] = {t4.x, t4.y};
    unsigned k2[2];
    float dv[7][2];
    #pragma unroll
    for (int e = 0; e < 2; ++e) {
      float obj = sigmoidf_(e4[e]);
      float tot = obj * cc[e];          // == sigmoid(obj)*sigmoid(max raw) bitwise
      k2[e] = fkey(tot >= 0.01f ? tot : -1.0f);
      int jj = j + e;
      int gy = jj / W, gx = jj - gy * W;
      float fs = (float)S;
      float cx = (e0[e] + (float)gx) * fs;
      float cy = (e1[e] + (float)gy) * fs;
      float w  = expf(e2[e]) * fs;
      float h  = expf(e3[e]) * fs;
      dv[0][e] = cx - 0.5f * w; dv[1][e] = cy - 0.5f * h;
      dv[2][e] = cx + 0.5f * w; dv[3][e] = cy + 0.5f * h;
      dv[4][e] = obj; dv[5][e] = cc[e]; dv[6][e] = (float)lab[e];
    }
    *(uint2*)(keys + (size_t)b * NPI + a) = make_uint2(k2[0], k2[1]);
    const size_t P  = (size_t)NIMG * NPI;
    const size_t pa = (size_t)b * NPI + a;
    #pragma unroll
    for (int c = 0; c < 7; ++c)
      *(float2*)(dets + (size_t)c * P + pa) = make_float2(dv[c][0], dv[c][1]);
    atomicAdd(&lh[k2[0] >> 22], 1u);
    atomicAdd(&lh[k2[1] >> 22], 1u);
  }
  __syncthreads();
  unsigned* gb = hist2 + (size_t)b * NGRP;
  for (int i = threadIdx.x; i < NGRP; i += 256) {
    unsigned v = lh[i];
    if (v) atomicAdd(&gb[i], v);
  }
}

// ---------------- Kernel 2: per-image select + rank-sort + gather + IoU + NMS ----
__global__ __launch_bounds__(1024) void k_post(
    const unsigned* __restrict__ hist2, const unsigned* __restrict__ keys,
    const float* __restrict__ dets, float* __restrict__ out)
{
  const int b    = blockIdx.x;
  const int tid  = threadIdx.x;
  const int lane = tid & 63;
  const int wave = tid >> 6;

  __shared__ unsigned lh[NGRP];                         // 4 KB coarse hist
  __shared__ unsigned sh_sub[4096];                     // 16 KB refine hist
  __shared__ unsigned sh_c64[64];
  __shared__ unsigned sh_G, sh_T;
  __shared__ __align__(16) unsigned long long sh_cand[CAP];     // 8 KB
  __shared__ unsigned long long sh_sorted[KTOP];        // 4 KB
  __shared__ float sh_det[KTOP][7];                     // 14 KB
  __shared__ float sbx1[512], sby1[512], sbx2[512], sby2[512], sar[512]; // 10 KB
  __shared__ unsigned sh_mask[KTOP * 16];               // 32 KB
  __shared__ unsigned sh_inval[16];
  __shared__ unsigned sh_keep[16];
  __shared__ unsigned sh_wcA[16], sh_wcB[16];
  __shared__ float sh_red[16];
  __shared__ float sh_maxc;

  // ---- Phase A1: load precomputed coarse hist; find boundary 10-bit group G
  lh[tid] = hist2[(size_t)b * NGRP + tid];
  for (int i = tid; i < 4096; i += 1024) sh_sub[i] = 0;
  __syncthreads();
  if (tid < 64) {
    unsigned s = 0;
    #pragma unroll
    for (int k = 0; k < 16; ++k) s += lh[tid * 16 + k];
    sh_c64[tid] = s;
  }
  __syncthreads();
  if (tid == 0) {
    unsigned cum = 0; int C = 0;
    for (int g = 63; g >= 0; --g) {
      unsigned v = sh_c64[g];
      if (cum + v >= KTOP) { C = g; break; }
      cum += v;
    }
    int G = C * 16; unsigned chi = cum;
    for (int g = C * 16 + 15; g >= C * 16; --g) {
      unsigned v = lh[g];
      if (chi + v >= KTOP) { G = g; break; }
      chi += v;
    }
    sh_G = (unsigned)G;
    sh_c64[0] = chi;                    // stash Chi10 for the T-search
  }
  __syncthreads();
  const unsigned G = sh_G;
  const unsigned* kb = keys + (size_t)b * NPI;

  // ---- Phase A2: 4096-bin sub-hist of bits [21:10] within group G
  for (int g = tid; g < NPI / 4; g += 1024) {
    uint4 kv = ((const uint4*)kb)[g];
    unsigned kk[4] = {kv.x, kv.y, kv.z, kv.w};
    #pragma unroll
    for (int e = 0; e < 4; ++e)
      if ((kk[e] >> 22) == G) atomicAdd(&sh_sub[(kk[e] >> 10) & 4095u], 1u);
  }
  __syncthreads();
  unsigned chi10 = sh_c64[0];
  __syncthreads();
  if (tid < 64) {
    unsigned s = 0;
    for (int k = 0; k < 64; ++k) s += sh_sub[tid * 64 + k];
    sh_c64[tid] = s;
  }
  __syncthreads();
  if (tid == 0) {
    unsigned c = chi10; int C2 = 0;
    for (int g = 63; g >= 0; --g) {
      unsigned v = sh_c64[g];
      if (c + v >= KTOP) { C2 = g; break; }
      c += v;
    }
    int T12 = C2 * 64;
    for (int t2 = C2 * 64 + 63; t2 >= C2 * 64; --t2) {
      unsigned v = sh_sub[t2];
      if (c + v >= KTOP) { T12 = t2; break; }
      c += v;
    }
    sh_T = (G << 12) | (unsigned)T12;   // 22-bit threshold
  }
  __syncthreads();
  const unsigned T = sh_T;

  // ---- Phase B1: per-wave counting (wave w owns groups [w*525,(w+1)*525))
  unsigned runA = 0, runB = 0;
  for (int it = 0; it < 9; ++it) {
    int gl = it * 64 + lane;
    bool act = (gl < GPW);
    int g = wave * GPW + gl;
    uint4 kv = act ? ((const uint4*)kb)[g] : make_uint4(0, 0, 0, 0);
    unsigned kk[4] = {kv.x, kv.y, kv.z, kv.w};
    #pragma unroll
    for (int e = 0; e < 4; ++e) {
      unsigned bin = kk[e] >> 10;
      runA += (unsigned)__popcll(__ballot(act && (bin > T)));
      runB += (unsigned)__popcll(__ballot(act && (bin == T)));
    }
  }
  if (lane == 0) { sh_wcA[wave] = runA; sh_wcB[wave] = runB; }
  __syncthreads();
  unsigned pA = 0, pB = 0, nA = 0, nBtot = 0;
  #pragma unroll
  for (int w2 = 0; w2 < 16; ++w2) {
    unsigned va = sh_wcA[w2], vb = sh_wcB[w2];
    if (w2 < wave) { pA += va; pB += vb; }
    nA += va; nBtot += vb;
  }
  const unsigned Bcap = CAP - nA;
  const unsigned nBk  = (nBtot < Bcap) ? nBtot : Bcap;
  const int nTot = (int)(nA + nBk);     // >= KTOP, <= CAP

  // ---- Phase B2: deterministic index-ordered write
  // A (bin>T) -> [0,nA); B (bin==T, lowest-index Bcap kept) -> [nA, nA+nBk)
  for (int it = 0; it < 9; ++it) {
    int gl = it * 64 + lane;
    bool act = (gl < GPW);
    int g = wave * GPW + gl;
    uint4 kv = act ? ((const uint4*)kb)[g] : make_uint4(0, 0, 0, 0);
    unsigned kk[4] = {kv.x, kv.y, kv.z, kv.w};
    bool iA[4], iB[4];
    unsigned long long balA[4], balB[4];
    #pragma unroll
    for (int e = 0; e < 4; ++e) {
      unsigned bin = kk[e] >> 10;
      iA[e] = act && (bin > T);
      iB[e] = act && (bin == T);
      balA[e] = __ballot(iA[e]);
      balB[e] = __ballot(iB[e]);
    }
    unsigned long long lt = (1ULL << lane) - 1ULL;
    unsigned pAl = pA, pBl = pB;
    #pragma unroll
    for (int e = 0; e < 4; ++e) {
      pAl += (unsigned)__popcll(balA[e] & lt);
      pBl += (unsigned)__popcll(balB[e] & lt);
    }
    #pragma unroll
    for (int e = 0; e < 4; ++e) {
      int a0 = g * 4 + e;
      unsigned long long packed =
          ((unsigned long long)kk[e] << 32) |
          (unsigned long long)(0xFFFFFFFFu - (unsigned)a0);
      if (iA[e]) { sh_cand[pAl] = packed; ++pAl; }
      if (iB[e]) { if (pBl < Bcap) sh_cand[nA + pBl] = packed; ++pBl; }
      pA += (unsigned)__popcll(balA[e]);
      pB += (unsigned)__popcll(balB[e]);
    }
  }
  __syncthreads();

  // ---- Phase C: rank-then-scatter (replaces bitonic; packed u64 all distinct)
  {
    unsigned long long cnd[16];
    #pragma unroll
    for (int k = 0; k < 16; ++k) cnd[k] = sh_cand[64 * k + lane];
    unsigned long long mine = sh_cand[tid];
    int rank = 0;
    #pragma unroll
    for (int k = 0; k < 16; ++k) {
      int base0 = 64 * k;
      if (base0 < nTot) {
        int lim = nTot - base0; if (lim > 64) lim = 64;
        for (int l = 0; l < lim; ++l)
          rank += (rdlane64(cnd[k], l) > mine) ? 1 : 0;
      }
    }
    if (tid < nTot && rank < KTOP) sh_sorted[rank] = mine;
  }
  __syncthreads();

  // ---- Phase D: gather top-500 dets; max_c; offset boxes (SoA); inval bits
  bool validk = false;
  float contrib = -INFINITY;
  float det[7];
  if (tid < KTOP) {
    unsigned long long v = sh_sorted[tid];
    unsigned keyk = (unsigned)(v >> 32);
    int a = (int)(0xFFFFFFFFu - (unsigned)(v & 0xFFFFFFFFull));
    const size_t P  = (size_t)NIMG * NPI;
    const size_t pa = (size_t)b * NPI + (size_t)a;
    #pragma unroll
    for (int c = 0; c < 7; ++c) det[c] = dets[(size_t)c * P + pa];
    #pragma unroll
    for (int c = 0; c < 7; ++c) sh_det[tid][c] = det[c];
    validk = (keyk >= KEY001);
    float m4 = fmaxf(fmaxf(det[0], det[1]), fmaxf(det[2], det[3]));
    contrib = validk ? m4 : 0.0f;     // jnp.where(valid, boxes, 0) then global max
  }
  float r = contrib;
  #pragma unroll
  for (int off = 32; off > 0; off >>= 1) r = fmaxf(r, __shfl_xor(r, off));
  if (lane == 0) sh_red[wave] = r;
  unsigned long long bv = __ballot((tid < KTOP) && !validk);
  if (wave < 8 && lane == 0) {
    sh_inval[wave * 2]     = (unsigned)(bv & 0xFFFFFFFFull);
    sh_inval[wave * 2 + 1] = (unsigned)(bv >> 32);
  }
  __syncthreads();
  if (tid == 0) {
    float m = -INFINITY;
    for (int w2 = 0; w2 < 16; ++w2) m = fmaxf(m, sh_red[w2]);
    sh_maxc = m + 1.0f;
  }
  __syncthreads();
  const float maxc = sh_maxc;
  if (tid < 512) {
    if (tid < KTOP) {
      float offb = det[6] * maxc;     // label * max_c
      float x1 = det[0] + offb, y1 = det[1] + offb;
      float x2 = det[2] + offb, y2 = det[3] + offb;
      sbx1[tid] = x1; sby1[tid] = y1; sbx2[tid] = x2; sby2[tid] = y2;
      sar[tid] = fmaxf(x2 - x1, 0.0f) * fmaxf(y2 - y1, 0.0f);   // from OFFSET box (ref)
    } else {
      sbx1[tid] = 0.0f; sby1[tid] = 0.0f; sbx2[tid] = 0.0f; sby2[tid] = 0.0f;
      sar[tid] = 0.0f;
    }
  }
  __syncthreads();

  // ---- Phase E: IoU bitmask via register-cached boxes + readlane (no LDS in loop)
  // wave w owns column block j in [w*32, w*32+32); lanes iterate i.
  {
    float cb1[8], cb2[8], cb3[8], cb4[8], car[8];
    #pragma unroll
    for (int k = 0; k < 8; ++k) {
      int j = 64 * k + lane;
      cb1[k] = sbx1[j]; cb2[k] = sby1[j]; cb3[k] = sbx2[j]; cb4[k] = sby2[j];
      car[k] = sar[j];
    }
    const int w = wave, jbase = w * 32, q = w >> 1, l0 = (w & 1) * 32;
    float jb1 = cb1[0], jb2 = cb2[0], jb3 = cb3[0], jb4 = cb4[0], jb5 = car[0];
    #pragma unroll
    for (int k = 1; k < 8; ++k)
      if (q == k) { jb1 = cb1[k]; jb2 = cb2[k]; jb3 = cb3[k]; jb4 = cb4[k]; jb5 = car[k]; }
    for (int it = 0; it < 8; ++it) {
      int i = it * 64 + lane;
      unsigned bits = 0u;
      if (jbase + 31 > it * 64) {       // uniform: block can contain j > i
        float ix1 = sbx1[i], iy1 = sby1[i], ix2 = sbx2[i], iy2 = sby2[i];
        float a1 = sar[i];
        #pragma unroll
        for (int jj = 0; jj < 32; ++jj) {
          int j = jbase + jj;
          float jx1 = rdlanef(jb1, l0 + jj);
          float jy1 = rdlanef(jb2, l0 + jj);
          float jx2 = rdlanef(jb3, l0 + jj);
          float jy2 = rdlanef(jb4, l0 + jj);
          float a2  = rdlanef(jb5, l0 + jj);
          if (j < KTOP && j > i) {
            float iw = fminf(ix2, jx2) - fmaxf(ix1, jx1);
            float ih = fminf(iy2, jy2) - fmaxf(iy1, jy1);
            float inter = fmaxf(iw, 0.0f) * fmaxf(ih, 0.0f);
            // iou > 0.65  <=>  inter > 0.65*(a1+a2-inter+1e-9)
            if (inter > 0.65f * (a1 + a2 - inter + 1e-9f)) bits |= (1u << jj);
          }
        }
      }
      if (i < KTOP) sh_mask[i * 16 + w] = bits;
    }
  }
  __syncthreads();

  // ---- Phase F: greedy sequential scan (wave 0); lane l<16 owns suppressed word l
  if (tid < 64) {
    unsigned sup   = (lane < 16) ? sh_inval[lane] : 0u;
    unsigned keepw = 0u;
    unsigned cur = (unsigned)__builtin_amdgcn_readlane((int)sup, 0);
    unsigned mA = (lane < 16) ? sh_mask[0 * 16 + lane] : 0u;
    unsigned mB = (lane < 16) ? sh_mask[1 * 16 + lane] : 0u;
    for (int i = 0; i < KTOP; i += 2) {
      bool ok = ((cur >> (i & 31)) & 1u) == 0u;
      if (ok) {
        sup |= mA;
        if (lane == (i >> 5)) keepw |= (1u << (i & 31));
      }
      cur = (unsigned)__builtin_amdgcn_readlane((int)sup, (i + 1) >> 5);
      mA = (lane < 16 && (i + 2) < KTOP) ? sh_mask[(i + 2) * 16 + lane] : 0u;
      bool ok2 = ((cur >> ((i + 1) & 31)) & 1u) == 0u;
      if (ok2) {
        sup |= mB;
        if (lane == ((i + 1) >> 5)) keepw |= (1u << ((i + 1) & 31));
      }
      cur = (unsigned)__builtin_amdgcn_readlane((int)sup, (i + 2) >> 5);
      mB = (lane < 16 && (i + 3) < KTOP) ? sh_mask[(i + 3) * 16 + lane] : 0u;
    }
    if (lane < 16) sh_keep[lane] = keepw;
  }
  __syncthreads();

  // ---- Phase G: write det * keep
  for (int x = tid; x < KTOP * 7; x += 1024) {
    int k = x / 7, c = x - k * 7;
    float keepf = ((sh_keep[k >> 5] >> (k & 31)) & 1u) ? 1.0f : 0.0f;
    out[(size_t)b * (KTOP * 7) + x] = sh_det[k][c] * keepf;
  }
}

extern "C" void kernel_launch(void* const* d_in, const int* in_sizes, int n_in,
                              void* d_out, int out_size, void* d_ws, size_t ws_size,
                              hipStream_t stream) {
  const float* p8  = (const float*)d_in[0];
  const float* p16 = (const float*)d_in[1];
  const float* p32 = (const float*)d_in[2];
  float* out = (float*)d_out;
  // workspace layout (~8.6 MB)
  unsigned* hist2 = (unsigned*)d_ws;                         // [8][1024]
  unsigned* keys  = hist2 + (size_t)NIMG * NGRP;             // [8][NPI]
  float*    dets  = (float*)(keys + (size_t)NIMG * NPI);     // [7][8][NPI]

  hipMemsetAsync(hist2, 0, (size_t)NIMG * NGRP * 4, stream);
  k_decode<<<dim3(66, NIMG), 256, 0, stream>>>(p8, p16, p32, keys, dets, hist2);
  k_post<<<dim3(NIMG), 1024, 0, stream>>>(hist2, keys, dets, out);
}

// Round 6
// 210.014 us; speedup vs baseline: 1.2098x; 1.2098x over previous
//
#include <hip/hip_runtime.h>

#define NPI    33600     // anchors per image: 160^2 + 80^2 + 40^2
#define KTOP   500
#define CAP    1024
#define KEY001 0xBC23D70Au   // monotonic key of 0.01f
#define NGRP   1024
#define NIMG   8
#define GPW    525       // uint4 groups per wave in phase B (NPI/4/16)

__device__ __forceinline__ float sigmoidf_(float x) {
  return 1.0f / (1.0f + expf(-x));
}
// monotonic float -> u32 key (order-preserving for all non-NaN floats)
__device__ __forceinline__ unsigned fkey(float f) {
  unsigned u = __float_as_uint(f);
  return (u & 0x80000000u) ? ~u : (u | 0x80000000u);
}

// ---------------- Kernel 1: channel-streaming decode (register state) ----------
// Block = 512 contiguous anchors of one level; per channel one coalesced float4
// load per thread (16B/lane); running cls-argmax kept in VGPRs; 16-deep batches.
__global__ __launch_bounds__(128) void k_decode(
    const float* __restrict__ p8, const float* __restrict__ p16,
    const float* __restrict__ p32,
    unsigned* __restrict__ keys, float* __restrict__ dets,
    unsigned* __restrict__ hist2)
{
  const int b  = blockIdx.y;
  const int tx = blockIdx.x;
  const float* lvl; int HW, W, S, j0, abase;
  if (tx < 50)      { lvl = p8;  HW = 25600; W = 160; S = 8;  j0 = tx * 512;        abase = 0; }
  else if (tx < 63) { lvl = p16; HW = 6400;  W = 80;  S = 16; j0 = (tx - 50) * 512; abase = 25600; }
  else              { lvl = p32; HW = 1600;  W = 40;  S = 32; j0 = (tx - 63) * 512; abase = 32000; }
  __shared__ unsigned lh[NGRP];
  for (int i = threadIdx.x; i < NGRP; i += 128) lh[i] = 0;
  __syncthreads();

  const int e = j0 + 4 * threadIdx.x;     // in-level element index (16B aligned)
  const bool act = (e < HW);
  if (act) {
    const float* base = lvl + (size_t)b * 85 * HW + e;
    float4 t0 = *(const float4*)(base);
    float4 t1 = *(const float4*)(base + (size_t)1 * HW);
    float4 t2 = *(const float4*)(base + (size_t)2 * HW);
    float4 t3 = *(const float4*)(base + (size_t)3 * HW);
    float4 t4 = *(const float4*)(base + (size_t)4 * HW);
    // exact per-class sigmoid argmax, first occurrence (strict >), channel order
    float cc[4] = {-1.0f, -1.0f, -1.0f, -1.0f};
    int   lab[4] = {0, 0, 0, 0};
    for (int c0 = 5; c0 < 85; c0 += 16) {       // 5 batches of 16 (80 = 5*16)
      float4 r[16];
      #pragma unroll
      for (int u = 0; u < 16; ++u)
        r[u] = *(const float4*)(base + (size_t)(c0 + u) * HW);
      #pragma unroll
      for (int u = 0; u < 16; ++u) {
        float s;
        s = sigmoidf_(r[u].x); if (s > cc[0]) { cc[0] = s; lab[0] = c0 + u - 5; }
        s = sigmoidf_(r[u].y); if (s > cc[1]) { cc[1] = s; lab[1] = c0 + u - 5; }
        s = sigmoidf_(r[u].z); if (s > cc[2]) { cc[2] = s; lab[2] = c0 + u - 5; }
        s = sigmoidf_(r[u].w); if (s > cc[3]) { cc[3] = s; lab[3] = c0 + u - 5; }
      }
    }
    float e0[4] = {t0.x, t0.y, t0.z, t0.w};
    float e1[4] = {t1.x, t1.y, t1.z, t1.w};
    float e2[4] = {t2.x, t2.y, t2.z, t2.w};
    float e3[4] = {t3.x, t3.y, t3.z, t3.w};
    float e4[4] = {t4.x, t4.y, t4.z, t4.w};
    unsigned k4[4];
    float dv[7][4];
    #pragma unroll
    for (int q = 0; q < 4; ++q) {
      float obj = sigmoidf_(e4[q]);
      float tot = obj * cc[q];          // == sigmoid(obj)*sigmoid(max raw) bitwise
      k4[q] = fkey(tot >= 0.01f ? tot : -1.0f);
      int jj = e + q;
      int gy = jj / W, gx = jj - gy * W;
      float fs = (float)S;
      float cx = (e0[q] + (float)gx) * fs;
      float cy = (e1[q] + (float)gy) * fs;
      float w  = expf(e2[q]) * fs;
      float h  = expf(e3[q]) * fs;
      dv[0][q] = cx - 0.5f * w; dv[1][q] = cy - 0.5f * h;
      dv[2][q] = cx + 0.5f * w; dv[3][q] = cy + 0.5f * h;
      dv[4][q] = obj; dv[5][q] = cc[q]; dv[6][q] = (float)lab[q];
    }
    const int a = abase + e;            // global anchor index
    *(uint4*)(keys + (size_t)b * NPI + a) = make_uint4(k4[0], k4[1], k4[2], k4[3]);
    const size_t P  = (size_t)NIMG * NPI;
    const size_t pa = (size_t)b * NPI + a;
    #pragma unroll
    for (int c = 0; c < 7; ++c)
      *(float4*)(dets + (size_t)c * P + pa) =
          make_float4(dv[c][0], dv[c][1], dv[c][2], dv[c][3]);
    #pragma unroll
    for (int q = 0; q < 4; ++q) atomicAdd(&lh[k4[q] >> 22], 1u);
  }
  __syncthreads();
  unsigned* gb = hist2 + (size_t)b * NGRP;
  for (int i = threadIdx.x; i < NGRP; i += 128) {
    unsigned v = lh[i];
    if (v) atomicAdd(&gb[i], v);
  }
}

// ---------------- Kernel 2: per-image select + sort + gather + export ----------
__global__ __launch_bounds__(1024) void k_select(
    const unsigned* __restrict__ hist2, const unsigned* __restrict__ keys,
    const float* __restrict__ dets,
    float* __restrict__ topdet, float* __restrict__ soa,
    unsigned* __restrict__ invalg)
{
  const int b    = blockIdx.x;
  const int tid  = threadIdx.x;
  const int lane = tid & 63;
  const int wave = tid >> 6;

  __shared__ unsigned lh[NGRP];                         // 4 KB coarse hist
  __shared__ unsigned sh_sub[4096];                     // 16 KB refine hist
  __shared__ unsigned sh_c64[64];
  __shared__ unsigned sh_G, sh_T;
  __shared__ __align__(16) unsigned long long sh_cand[CAP];   // 8 KB
  __shared__ float sh_det[KTOP][7];                     // 14 KB
  __shared__ unsigned sh_inval[16];
  __shared__ unsigned sh_wcA[16], sh_wcB[16];
  __shared__ float sh_red[16];
  __shared__ float sh_maxc;

  // ---- Phase A1: load precomputed coarse hist; find boundary 10-bit group G
  lh[tid] = hist2[(size_t)b * NGRP + tid];
  for (int i = tid; i < 4096; i += 1024) sh_sub[i] = 0;
  __syncthreads();
  if (tid < 64) {
    unsigned s = 0;
    #pragma unroll
    for (int k = 0; k < 16; ++k) s += lh[tid * 16 + k];
    sh_c64[tid] = s;
  }
  __syncthreads();
  if (tid == 0) {
    unsigned cum = 0; int C = 0;
    for (int g = 63; g >= 0; --g) {
      unsigned v = sh_c64[g];
      if (cum + v >= KTOP) { C = g; break; }
      cum += v;
    }
    int G = C * 16; unsigned chi = cum;
    for (int g = C * 16 + 15; g >= C * 16; --g) {
      unsigned v = lh[g];
      if (chi + v >= KTOP) { G = g; break; }
      chi += v;
    }
    sh_G = (unsigned)G;
    sh_c64[0] = chi;                    // stash Chi10 for the T-search
  }
  __syncthreads();
  const unsigned G = sh_G;
  const unsigned* kb = keys + (size_t)b * NPI;

  // ---- Phase A2: 4096-bin sub-hist of bits [21:10] within group G
  for (int g = tid; g < NPI / 4; g += 1024) {
    uint4 kv = ((const uint4*)kb)[g];
    unsigned kk[4] = {kv.x, kv.y, kv.z, kv.w};
    #pragma unroll
    for (int q = 0; q < 4; ++q)
      if ((kk[q] >> 22) == G) atomicAdd(&sh_sub[(kk[q] >> 10) & 4095u], 1u);
  }
  __syncthreads();
  unsigned chi10 = sh_c64[0];
  __syncthreads();
  if (tid < 64) {
    unsigned s = 0;
    for (int k = 0; k < 64; ++k) s += sh_sub[tid * 64 + k];
    sh_c64[tid] = s;
  }
  __syncthreads();
  if (tid == 0) {
    unsigned c = chi10; int C2 = 0;
    for (int g = 63; g >= 0; --g) {
      unsigned v = sh_c64[g];
      if (c + v >= KTOP) { C2 = g; break; }
      c += v;
    }
    int T12 = C2 * 64;
    for (int t2 = C2 * 64 + 63; t2 >= C2 * 64; --t2) {
      unsigned v = sh_sub[t2];
      if (c + v >= KTOP) { T12 = t2; break; }
      c += v;
    }
    sh_T = (G << 12) | (unsigned)T12;   // 22-bit threshold
  }
  __syncthreads();
  const unsigned T = sh_T;

  // ---- Phase B1: per-wave counting (wave w owns groups [w*525,(w+1)*525))
  unsigned runA = 0, runB = 0;
  for (int it = 0; it < 9; ++it) {
    int gl = it * 64 + lane;
    bool act = (gl < GPW);
    int g = wave * GPW + gl;
    uint4 kv = act ? ((const uint4*)kb)[g] : make_uint4(0, 0, 0, 0);
    unsigned kk[4] = {kv.x, kv.y, kv.z, kv.w};
    #pragma unroll
    for (int q = 0; q < 4; ++q) {
      unsigned bin = kk[q] >> 10;
      runA += (unsigned)__popcll(__ballot(act && (bin > T)));
      runB += (unsigned)__popcll(__ballot(act && (bin == T)));
    }
  }
  if (lane == 0) { sh_wcA[wave] = runA; sh_wcB[wave] = runB; }
  __syncthreads();
  unsigned pA = 0, pB = 0, nA = 0, nBtot = 0;
  #pragma unroll
  for (int w2 = 0; w2 < 16; ++w2) {
    unsigned va = sh_wcA[w2], vb = sh_wcB[w2];
    if (w2 < wave) { pA += va; pB += vb; }
    nA += va; nBtot += vb;
  }
  const unsigned Bcap = CAP - nA;
  const unsigned nBk  = (nBtot < Bcap) ? nBtot : Bcap;
  const int nTot = (int)(nA + nBk);     // >= KTOP, <= CAP

  // ---- Phase B2: deterministic index-ordered write
  // A (bin>T) -> [0,nA); B (bin==T, lowest-index Bcap kept) -> [nA, nA+nBk)
  for (int it = 0; it < 9; ++it) {
    int gl = it * 64 + lane;
    bool act = (gl < GPW);
    int g = wave * GPW + gl;
    uint4 kv = act ? ((const uint4*)kb)[g] : make_uint4(0, 0, 0, 0);
    unsigned kk[4] = {kv.x, kv.y, kv.z, kv.w};
    bool iA[4], iB[4];
    unsigned long long balA[4], balB[4];
    #pragma unroll
    for (int q = 0; q < 4; ++q) {
      unsigned bin = kk[q] >> 10;
      iA[q] = act && (bin > T);
      iB[q] = act && (bin == T);
      balA[q] = __ballot(iA[q]);
      balB[q] = __ballot(iB[q]);
    }
    unsigned long long lt = (1ULL << lane) - 1ULL;
    unsigned pAl = pA, pBl = pB;
    #pragma unroll
    for (int q = 0; q < 4; ++q) {
      pAl += (unsigned)__popcll(balA[q] & lt);
      pBl += (unsigned)__popcll(balB[q] & lt);
    }
    #pragma unroll
    for (int q = 0; q < 4; ++q) {
      int a0 = g * 4 + q;
      unsigned long long packed =
          ((unsigned long long)kk[q] << 32) |
          (unsigned long long)(0xFFFFFFFFu - (unsigned)a0);
      if (iA[q]) { sh_cand[pAl] = packed; ++pAl; }
      if (iB[q]) { if (pBl < Bcap) sh_cand[nA + pBl] = packed; ++pBl; }
      pA += (unsigned)__popcll(balA[q]);
      pB += (unsigned)__popcll(balB[q]);
    }
  }
  __syncthreads();
  for (int s = nTot + tid; s < CAP; s += 1024) sh_cand[s] = 0ULL;
  __syncthreads();

  // ---- Phase C: bitonic sort 1024 u64 descending ((score desc, index asc))
  for (unsigned kk2 = 2; kk2 <= CAP; kk2 <<= 1) {
    for (unsigned jj = kk2 >> 1; jj > 0; jj >>= 1) {
      unsigned i = (unsigned)tid, p = i ^ jj;
      if (p > i) {
        unsigned long long x = sh_cand[i], y = sh_cand[p];
        bool desc = ((i & kk2) == 0);
        if ((x < y) == desc) { sh_cand[i] = y; sh_cand[p] = x; }
      }
      __syncthreads();
    }
  }

  // ---- Phase D: gather top-500 dets; max_c; inval bits; export
  bool validk = false;
  float contrib = -INFINITY;
  float det[7] = {0, 0, 0, 0, 0, 0, 0};
  if (tid < KTOP) {
    unsigned long long v = sh_cand[tid];
    unsigned keyk = (unsigned)(v >> 32);
    int a = (int)(0xFFFFFFFFu - (unsigned)(v & 0xFFFFFFFFull));
    if (a < 0) a = 0;                 // zero-padded slot (invalid anyway)
    const size_t P  = (size_t)NIMG * NPI;
    const size_t pa = (size_t)b * NPI + (size_t)a;
    #pragma unroll
    for (int c = 0; c < 7; ++c) det[c] = dets[(size_t)c * P + pa];
    #pragma unroll
    for (int c = 0; c < 7; ++c) sh_det[tid][c] = det[c];
    validk = (keyk >= KEY001);
    float m4 = fmaxf(fmaxf(det[0], det[1]), fmaxf(det[2], det[3]));
    contrib = validk ? m4 : 0.0f;     // jnp.where(valid, boxes, 0) then global max
  }
  float r = contrib;
  #pragma unroll
  for (int off = 32; off > 0; off >>= 1) r = fmaxf(r, __shfl_xor(r, off));
  if (lane == 0) sh_red[wave] = r;
  unsigned long long bv = __ballot((tid < KTOP) && !validk);
  if (wave < 8 && lane == 0) {
    sh_inval[wave * 2]     = (unsigned)(bv & 0xFFFFFFFFull);
    sh_inval[wave * 2 + 1] = (unsigned)(bv >> 32);
  }
  __syncthreads();
  if (tid == 0) {
    float m = -INFINITY;
    for (int w2 = 0; w2 < 16; ++w2) m = fmaxf(m, sh_red[w2]);
    sh_maxc = m + 1.0f;
  }
  __syncthreads();
  const float maxc = sh_maxc;
  if (tid < 512) {
    float x1, y1, x2, y2, ar;
    if (tid < KTOP) {
      float offb = det[6] * maxc;     // label * max_c
      x1 = det[0] + offb; y1 = det[1] + offb;
      x2 = det[2] + offb; y2 = det[3] + offb;
      ar = fmaxf(x2 - x1, 0.0f) * fmaxf(y2 - y1, 0.0f);   // from OFFSET box (ref)
    } else { x1 = y1 = x2 = y2 = ar = 0.0f; }
    soa[(0 * NIMG + b) * 512 + tid] = x1;
    soa[(1 * NIMG + b) * 512 + tid] = y1;
    soa[(2 * NIMG + b) * 512 + tid] = x2;
    soa[(3 * NIMG + b) * 512 + tid] = y2;
    soa[(4 * NIMG + b) * 512 + tid] = ar;
  }
  if (tid < 16) invalg[b * 16 + tid] = sh_inval[tid];
  for (int x = tid; x < KTOP * 7; x += 1024)
    topdet[(size_t)b * (KTOP * 7) + x] = ((const float*)sh_det)[x];
}

// ---------------- Kernel 3: IoU suppression bitmask (16 x 8 blocks) ----------
__global__ __launch_bounds__(256) void k_iou(
    const float* __restrict__ soa, unsigned* __restrict__ gmask)
{
  const int w = blockIdx.x, b = blockIdx.y;
  const int tid = threadIdx.x;
  __shared__ float sx1[512], sy1[512], sx2[512], sy2[512], sa[512];
  for (int x = tid; x < 512; x += 256) {
    sx1[x] = soa[(0 * NIMG + b) * 512 + x];
    sy1[x] = soa[(1 * NIMG + b) * 512 + x];
    sx2[x] = soa[(2 * NIMG + b) * 512 + x];
    sy2[x] = soa[(3 * NIMG + b) * 512 + x];
    sa[x]  = soa[(4 * NIMG + b) * 512 + x];
  }
  __syncthreads();
  const int jbase = w * 32;
  for (int i = tid; i < KTOP; i += 256) {
    unsigned bits = 0u;
    if (jbase + 31 > i) {
      float ix1 = sx1[i], iy1 = sy1[i], ix2 = sx2[i], iy2 = sy2[i];
      float a1 = sa[i];
      #pragma unroll 4
      for (int jj = 0; jj < 32; ++jj) {
        int j = jbase + jj;
        if (j < KTOP && j > i) {
          float jx1 = sx1[j], jy1 = sy1[j];       // j uniform -> LDS broadcast
          float jx2 = sx2[j], jy2 = sy2[j];
          float a2  = sa[j];
          float iw = fminf(ix2, jx2) - fmaxf(ix1, jx1);
          float ih = fminf(iy2, jy2) - fmaxf(iy1, jy1);
          float inter = fmaxf(iw, 0.0f) * fmaxf(ih, 0.0f);
          // iou > 0.65  <=>  inter > 0.65*(a1+a2-inter+1e-9)
          if (inter > 0.65f * (a1 + a2 - inter + 1e-9f)) bits |= (1u << jj);
        }
      }
    }
    gmask[((size_t)b * 16 + w) * 512 + i] = bits;   // [b][w][i], coalesced
  }
}

// ---------------- Kernel 4: greedy scan + final write (8 blocks) ----------
__global__ __launch_bounds__(256) void k_nms(
    const unsigned* __restrict__ gmask, const unsigned* __restrict__ invalg,
    const float* __restrict__ topdet, float* __restrict__ out)
{
  const int b = blockIdx.x;
  const int tid = threadIdx.x;
  const int lane = tid & 63;
  __shared__ unsigned sm[KTOP * 17];     // [i][w], stride 17 -> conflict-free
  __shared__ unsigned sh_keep[16];
  for (int g = tid; g < KTOP * 16; g += 256) {
    int w = g / KTOP, i = g - w * KTOP;
    sm[i * 17 + w] = gmask[((size_t)b * 16 + w) * 512 + i];
  }
  __syncthreads();
  if (tid < 64) {
    unsigned sup   = (lane < 16) ? invalg[b * 16 + lane] : 0u;
    unsigned keepw = 0u;
    unsigned cur = (unsigned)__builtin_amdgcn_readlane((int)sup, 0);
    unsigned mA = (lane < 16) ? sm[0 * 17 + lane] : 0u;
    unsigned mB = (lane < 16) ? sm[1 * 17 + lane] : 0u;
    for (int i = 0; i < KTOP; i += 2) {
      bool ok = ((cur >> (i & 31)) & 1u) == 0u;
      if (ok) {
        sup |= mA;
        if (lane == (i >> 5)) keepw |= (1u << (i & 31));
      }
      cur = (unsigned)__builtin_amdgcn_readlane((int)sup, (i + 1) >> 5);
      mA = (lane < 16 && (i + 2) < KTOP) ? sm[(i + 2) * 17 + lane] : 0u;
      bool ok2 = ((cur >> ((i + 1) & 31)) & 1u) == 0u;
      if (ok2) {
        sup |= mB;
        if (lane == ((i + 1) >> 5)) keepw |= (1u << ((i + 1) & 31));
      }
      cur = (unsigned)__builtin_amdgcn_readlane((int)sup, (i + 2) >> 5);
      mB = (lane < 16 && (i + 3) < KTOP) ? sm[(i + 3) * 17 + lane] : 0u;
    }
    if (lane < 16) sh_keep[lane] = keepw;
  }
  __syncthreads();
  for (int x = tid; x < KTOP * 7; x += 256) {
    int k = x / 7;
    float keepf = ((sh_keep[k >> 5] >> (k & 31)) & 1u) ? 1.0f : 0.0f;
    out[(size_t)b * (KTOP * 7) + x] = topdet[(size_t)b * (KTOP * 7) + x] * keepf;
  }
}

extern "C" void kernel_launch(void* const* d_in, const int* in_sizes, int n_in,
                              void* d_out, int out_size, void* d_ws, size_t ws_size,
                              hipStream_t stream) {
  const float* p8  = (const float*)d_in[0];
  const float* p16 = (const float*)d_in[1];
  const float* p32 = (const float*)d_in[2];
  float* out = (float*)d_out;
  // workspace layout (~9.1 MB)
  unsigned* hist2  = (unsigned*)d_ws;                          // [8][1024]
  unsigned* keys   = hist2 + (size_t)NIMG * NGRP;              // [8][NPI]
  float*    dets   = (float*)(keys + (size_t)NIMG * NPI);      // [7][8*NPI]
  float*    topdet = dets + (size_t)7 * NIMG * NPI;            // [8][500*7]
  float*    soa    = topdet + (size_t)NIMG * KTOP * 7;         // [5][8][512]
  unsigned* invalg = (unsigned*)(soa + (size_t)5 * NIMG * 512);// [8][16]
  unsigned* gmask  = invalg + NIMG * 16;                       // [8][16][512]

  hipMemsetAsync(hist2, 0, (size_t)NIMG * NGRP * 4, stream);
  k_decode<<<dim3(67, NIMG), 128, 0, stream>>>(p8, p16, p32, keys, dets, hist2);
  k_select<<<dim3(NIMG), 1024, 0, stream>>>(hist2, keys, dets, topdet, soa, invalg);
  k_iou<<<dim3(16, NIMG), 256, 0, stream>>>(soa, gmask);
  k_nms<<<dim3(NIMG), 256, 0, stream>>>(gmask, invalg, topdet, out);
}

// Round 7
// 201.866 us; speedup vs baseline: 1.2587x; 1.0404x over previous
//
#include <hip/hip_runtime.h>

#define NPI    33600     // anchors per image: 160^2 + 80^2 + 40^2
#define KTOP   500
#define CAP    1024
#define KEY001 0xBC23D70Au   // monotonic key of 0.01f
#define NGRP   1024
#define NIMG   8
#define GPW    525       // uint4 groups per wave in phase B (NPI/4/16)

__device__ __forceinline__ float sigmoidf_(float x) {
  return 1.0f / (1.0f + expf(-x));
}
// monotonic float -> u32 key (order-preserving for all non-NaN floats)
__device__ __forceinline__ unsigned fkey(float f) {
  unsigned u = __float_as_uint(f);
  return (u & 0x80000000u) ? ~u : (u | 0x80000000u);
}

// ---------------- Kernel 1: streaming score pass (keys + coarse hist only) -------
// Reads only channels 4..84. 2 anchors/thread, float2 loads, 16-deep batches.
// key = sigmoid(obj)*sigmoid(max raw cls) == obj*max(sigmoid(cls)) bitwise
// (sigmoid monotone non-decreasing) — proven absmax-0 in rounds 1-6.
__global__ __launch_bounds__(256) void k_score(
    const float* __restrict__ p8, const float* __restrict__ p16,
    const float* __restrict__ p32,
    unsigned* __restrict__ keys, unsigned* __restrict__ hist2)
{
  const int b  = blockIdx.y;
  const int tx = blockIdx.x;
  const float* lvl; int HW, j0, abase;
  if (tx < 50)      { lvl = p8;  HW = 25600; j0 = tx * 512;        abase = 0; }
  else if (tx < 63) { lvl = p16; HW = 6400;  j0 = (tx - 50) * 512; abase = 25600; }
  else              { lvl = p32; HW = 1600;  j0 = (tx - 63) * 512; abase = 32000; }
  __shared__ unsigned lh[NGRP];
  for (int i = threadIdx.x; i < NGRP; i += 256) lh[i] = 0;
  __syncthreads();

  const int e = j0 + 2 * threadIdx.x;
  if (e < HW) {
    const float* base = lvl + (size_t)b * 85 * HW + e;
    float2 o2 = *(const float2*)(base + (size_t)4 * HW);
    float m0 = -INFINITY, m1 = -INFINITY;
    for (int c0 = 5; c0 < 85; c0 += 16) {      // 5 batches of 16 channels
      float2 r[16];
      #pragma unroll
      for (int u = 0; u < 16; ++u)
        r[u] = *(const float2*)(base + (size_t)(c0 + u) * HW);
      #pragma unroll
      for (int u = 0; u < 16; ++u) { m0 = fmaxf(m0, r[u].x); m1 = fmaxf(m1, r[u].y); }
    }
    float s0 = sigmoidf_(o2.x) * sigmoidf_(m0);
    float s1 = sigmoidf_(o2.y) * sigmoidf_(m1);
    unsigned k0 = fkey(s0 >= 0.01f ? s0 : -1.0f);
    unsigned k1 = fkey(s1 >= 0.01f ? s1 : -1.0f);
    *(uint2*)(keys + (size_t)b * NPI + abase + e) = make_uint2(k0, k1);
    atomicAdd(&lh[k0 >> 22], 1u);
    atomicAdd(&lh[k1 >> 22], 1u);
  }
  __syncthreads();
  unsigned* gb = hist2 + (size_t)b * NGRP;
  for (int i = threadIdx.x; i < NGRP; i += 256) {
    unsigned v = lh[i];
    if (v) atomicAdd(&gb[i], v);
  }
}

// ---------------- Kernel 2: per-image select + sort -> selected anchor list -----
__global__ __launch_bounds__(1024) void k_select(
    const unsigned* __restrict__ hist2, const unsigned* __restrict__ keys,
    unsigned* __restrict__ selanch, unsigned* __restrict__ invalg)
{
  const int b    = blockIdx.x;
  const int tid  = threadIdx.x;
  const int lane = tid & 63;
  const int wave = tid >> 6;

  __shared__ unsigned lh[NGRP];                         // 4 KB coarse hist
  __shared__ unsigned sh_sub[4096];                     // 16 KB refine hist
  __shared__ unsigned sh_c64[64];
  __shared__ unsigned sh_G, sh_T;
  __shared__ __align__(16) unsigned long long sh_cand[CAP];   // 8 KB
  __shared__ unsigned sh_inval[16];
  __shared__ unsigned sh_wcA[16], sh_wcB[16];

  // ---- Phase A1: coarse hist -> boundary 10-bit group G
  lh[tid] = hist2[(size_t)b * NGRP + tid];
  for (int i = tid; i < 4096; i += 1024) sh_sub[i] = 0;
  __syncthreads();
  if (tid < 64) {
    unsigned s = 0;
    #pragma unroll
    for (int k = 0; k < 16; ++k) s += lh[tid * 16 + k];
    sh_c64[tid] = s;
  }
  __syncthreads();
  if (tid == 0) {
    unsigned cum = 0; int C = 0;
    for (int g = 63; g >= 0; --g) {
      unsigned v = sh_c64[g];
      if (cum + v >= KTOP) { C = g; break; }
      cum += v;
    }
    int G = C * 16; unsigned chi = cum;
    for (int g = C * 16 + 15; g >= C * 16; --g) {
      unsigned v = lh[g];
      if (chi + v >= KTOP) { G = g; break; }
      chi += v;
    }
    sh_G = (unsigned)G;
    sh_c64[0] = chi;                    // stash Chi10 for the T-search
  }
  __syncthreads();
  const unsigned G = sh_G;
  const unsigned* kb = keys + (size_t)b * NPI;

  // ---- Phase A2: 4096-bin sub-hist of bits [21:10] within group G
  for (int g = tid; g < NPI / 4; g += 1024) {
    uint4 kv = ((const uint4*)kb)[g];
    unsigned kk[4] = {kv.x, kv.y, kv.z, kv.w};
    #pragma unroll
    for (int q = 0; q < 4; ++q)
      if ((kk[q] >> 22) == G) atomicAdd(&sh_sub[(kk[q] >> 10) & 4095u], 1u);
  }
  __syncthreads();
  unsigned chi10 = sh_c64[0];
  __syncthreads();
  if (tid < 64) {
    unsigned s = 0;
    for (int k = 0; k < 64; ++k) s += sh_sub[tid * 64 + k];
    sh_c64[tid] = s;
  }
  __syncthreads();
  if (tid == 0) {
    unsigned c = chi10; int C2 = 0;
    for (int g = 63; g >= 0; --g) {
      unsigned v = sh_c64[g];
      if (c + v >= KTOP) { C2 = g; break; }
      c += v;
    }
    int T12 = C2 * 64;
    for (int t2 = C2 * 64 + 63; t2 >= C2 * 64; --t2) {
      unsigned v = sh_sub[t2];
      if (c + v >= KTOP) { T12 = t2; break; }
      c += v;
    }
    sh_T = (G << 12) | (unsigned)T12;   // 22-bit threshold
  }
  __syncthreads();
  const unsigned T = sh_T;

  // ---- Phase B1: per-wave counting (wave w owns groups [w*525,(w+1)*525))
  unsigned runA = 0, runB = 0;
  for (int it = 0; it < 9; ++it) {
    int gl = it * 64 + lane;
    bool act = (gl < GPW);
    int g = wave * GPW + gl;
    uint4 kv = act ? ((const uint4*)kb)[g] : make_uint4(0, 0, 0, 0);
    unsigned kk[4] = {kv.x, kv.y, kv.z, kv.w};
    #pragma unroll
    for (int q = 0; q < 4; ++q) {
      unsigned bin = kk[q] >> 10;
      runA += (unsigned)__popcll(__ballot(act && (bin > T)));
      runB += (unsigned)__popcll(__ballot(act && (bin == T)));
    }
  }
  if (lane == 0) { sh_wcA[wave] = runA; sh_wcB[wave] = runB; }
  __syncthreads();
  unsigned pA = 0, pB = 0, nA = 0, nBtot = 0;
  #pragma unroll
  for (int w2 = 0; w2 < 16; ++w2) {
    unsigned va = sh_wcA[w2], vb = sh_wcB[w2];
    if (w2 < wave) { pA += va; pB += vb; }
    nA += va; nBtot += vb;
  }
  const unsigned Bcap = CAP - nA;
  const unsigned nBk  = (nBtot < Bcap) ? nBtot : Bcap;
  const int nTot = (int)(nA + nBk);     // >= KTOP, <= CAP

  // ---- Phase B2: deterministic index-ordered write
  for (int it = 0; it < 9; ++it) {
    int gl = it * 64 + lane;
    bool act = (gl < GPW);
    int g = wave * GPW + gl;
    uint4 kv = act ? ((const uint4*)kb)[g] : make_uint4(0, 0, 0, 0);
    unsigned kk[4] = {kv.x, kv.y, kv.z, kv.w};
    bool iA[4], iB[4];
    unsigned long long balA[4], balB[4];
    #pragma unroll
    for (int q = 0; q < 4; ++q) {
      unsigned bin = kk[q] >> 10;
      iA[q] = act && (bin > T);
      iB[q] = act && (bin == T);
      balA[q] = __ballot(iA[q]);
      balB[q] = __ballot(iB[q]);
    }
    unsigned long long lt = (1ULL << lane) - 1ULL;
    unsigned pAl = pA, pBl = pB;
    #pragma unroll
    for (int q = 0; q < 4; ++q) {
      pAl += (unsigned)__popcll(balA[q] & lt);
      pBl += (unsigned)__popcll(balB[q] & lt);
    }
    #pragma unroll
    for (int q = 0; q < 4; ++q) {
      int a0 = g * 4 + q;
      unsigned long long packed =
          ((unsigned long long)kk[q] << 32) |
          (unsigned long long)(0xFFFFFFFFu - (unsigned)a0);
      if (iA[q]) { sh_cand[pAl] = packed; ++pAl; }
      if (iB[q]) { if (pBl < Bcap) sh_cand[nA + pBl] = packed; ++pBl; }
      pA += (unsigned)__popcll(balA[q]);
      pB += (unsigned)__popcll(balB[q]);
    }
  }
  __syncthreads();
  for (int s = nTot + tid; s < CAP; s += 1024) sh_cand[s] = 0ULL;
  __syncthreads();

  // ---- Phase C: bitonic sort 1024 u64 descending ((score desc, index asc))
  for (unsigned kk2 = 2; kk2 <= CAP; kk2 <<= 1) {
    for (unsigned jj = kk2 >> 1; jj > 0; jj >>= 1) {
      unsigned i = (unsigned)tid, p = i ^ jj;
      if (p > i) {
        unsigned long long x = sh_cand[i], y = sh_cand[p];
        bool desc = ((i & kk2) == 0);
        if ((x < y) == desc) { sh_cand[i] = y; sh_cand[p] = x; }
      }
      __syncthreads();
    }
  }

  // ---- Phase D: export selected anchors + invalid bitset
  if (tid < KTOP) {
    unsigned long long v = sh_cand[tid];
    unsigned keyk = (unsigned)(v >> 32);
    int a = (int)(0xFFFFFFFFu - (unsigned)(v & 0xFFFFFFFFull));
    if (a < 0) a = 0;                 // zero-padded slot (invalid anyway)
    selanch[b * KTOP + tid] = (unsigned)a;
    bool validk = (keyk >= KEY001);
    unsigned long long bv = __ballot(!validk);
    if (lane == 0) {
      sh_inval[wave * 2]     = (unsigned)(bv & 0xFFFFFFFFull);
      sh_inval[wave * 2 + 1] = (unsigned)(bv >> 32);
    }
  } else {
    unsigned long long bv = __ballot(false);
    (void)bv;
  }
  __syncthreads();
  if (tid < 16) invalg[b * 16 + tid] = sh_inval[tid];
}

// ---------------- Kernel 3: decode selected anchors only (exact math) ----------
// 16 lanes per selected anchor; per-class sigmoid argmax with first-occurrence
// preserving reduce (tie -> smaller class index). grid (8 parts, NIMG).
__global__ __launch_bounds__(256) void k_gather(
    const float* __restrict__ p8, const float* __restrict__ p16,
    const float* __restrict__ p32,
    const unsigned* __restrict__ selanch, float* __restrict__ seldet)
{
  const int b    = blockIdx.y;
  const int part = blockIdx.x;
  const int tid  = threadIdx.x;
  const int p    = tid & 15;            // lane within 16-lane group
  const int grp  = tid >> 4;            // 16 groups per 256 threads
  const int lane = tid & 63;
  const int g0   = lane & ~15;          // group base lane within wave

  for (int iter = 0; iter < 4; ++iter) {
    int s = part * 64 + iter * 16 + grp;
    if (s >= KTOP) continue;
    int a = (int)selanch[b * KTOP + s];
    const float* lvl; int j, W, HW, S;
    if (a < 25600)      { lvl = p8;  j = a;         W = 160; HW = 25600; S = 8;  }
    else if (a < 32000) { lvl = p16; j = a - 25600; W = 80;  HW = 6400;  S = 16; }
    else                { lvl = p32; j = a - 32000; W = 40;  HW = 1600;  S = 32; }
    const float* base = lvl + (size_t)b * 85 * HW + j;
    // lane p owns classes {p, p+16, p+32, p+48, p+64} (ascending -> first occ)
    float cc = -1.0f; int lab = 0;
    #pragma unroll
    for (int u = 0; u < 5; ++u) {
      int c = p + 16 * u;
      float sv = sigmoidf_(base[(size_t)(5 + c) * HW]);
      if (sv > cc) { cc = sv; lab = c; }    // strict > : first occurrence
    }
    float tload = (p < 5) ? base[(size_t)p * HW] : 0.0f;
    // 16-lane reduce: max cc, ties -> smaller class index (= first occurrence)
    #pragma unroll
    for (int off = 1; off < 16; off <<= 1) {
      float occ = __shfl_xor(cc, off);
      int  olb = __shfl_xor(lab, off);
      if (occ > cc || (occ == cc && olb < lab)) { cc = occ; lab = olb; }
    }
    float t0 = __shfl(tload, g0 + 0);
    float t1 = __shfl(tload, g0 + 1);
    float t2 = __shfl(tload, g0 + 2);
    float t3 = __shfl(tload, g0 + 3);
    float t4 = __shfl(tload, g0 + 4);
    if (p == 0) {
      int gy = j / W, gx = j - gy * W;
      float fs = (float)S;
      float cx = (t0 + (float)gx) * fs;
      float cy = (t1 + (float)gy) * fs;
      float w  = expf(t2) * fs;
      float h  = expf(t3) * fs;
      float obj = sigmoidf_(t4);
      float* d = seldet + ((size_t)b * KTOP + s) * 7;
      d[0] = cx - 0.5f * w; d[1] = cy - 0.5f * h;
      d[2] = cx + 0.5f * w; d[3] = cy + 0.5f * h;
      d[4] = obj; d[5] = cc; d[6] = (float)lab;
    }
  }
}

// ---------------- Kernel 4: max_c + box offsets + IoU bitmask (16 x 8 blocks) ---
__global__ __launch_bounds__(256) void k_iou(
    const float* __restrict__ seldet, const unsigned* __restrict__ invalg,
    unsigned* __restrict__ gmask)
{
  const int w = blockIdx.x, b = blockIdx.y;
  const int tid = threadIdx.x;
  const int lane = tid & 63;
  const int wave = tid >> 6;
  __shared__ float sd[KTOP * 7];        // 14 KB det stage
  __shared__ float sx1[512], sy1[512], sx2[512], sy2[512], sa[512];
  __shared__ float sred[4];
  __shared__ float smaxc;
  for (int x = tid; x < KTOP * 7; x += 256)
    sd[x] = seldet[(size_t)b * (KTOP * 7) + x];
  __syncthreads();
  // max over valid boxes of max(x1,y1,x2,y2); invalid contribute 0 (ref where())
  float contrib = 0.0f;
  for (int i = tid; i < KTOP; i += 256) {
    bool valid = ((invalg[b * 16 + (i >> 5)] >> (i & 31)) & 1u) == 0u;
    float m4 = fmaxf(fmaxf(sd[i * 7 + 0], sd[i * 7 + 1]),
                     fmaxf(sd[i * 7 + 2], sd[i * 7 + 3]));
    contrib = fmaxf(contrib, valid ? m4 : 0.0f);
  }
  #pragma unroll
  for (int off = 32; off > 0; off >>= 1) contrib = fmaxf(contrib, __shfl_xor(contrib, off));
  if (lane == 0) sred[wave] = contrib;
  __syncthreads();
  if (tid == 0) smaxc = fmaxf(fmaxf(sred[0], sred[1]), fmaxf(sred[2], sred[3])) + 1.0f;
  __syncthreads();
  const float maxc = smaxc;
  for (int i = tid; i < 512; i += 256) {
    float x1, y1, x2, y2, ar;
    if (i < KTOP) {
      float offb = sd[i * 7 + 6] * maxc;    // label * max_c
      x1 = sd[i * 7 + 0] + offb; y1 = sd[i * 7 + 1] + offb;
      x2 = sd[i * 7 + 2] + offb; y2 = sd[i * 7 + 3] + offb;
      ar = fmaxf(x2 - x1, 0.0f) * fmaxf(y2 - y1, 0.0f);   // area of OFFSET box (ref)
    } else { x1 = y1 = x2 = y2 = ar = 0.0f; }
    sx1[i] = x1; sy1[i] = y1; sx2[i] = x2; sy2[i] = y2; sa[i] = ar;
  }
  __syncthreads();
  const int jbase = w * 32;
  for (int i = tid; i < KTOP; i += 256) {
    unsigned bits = 0u;
    if (jbase + 31 > i) {
      float ix1 = sx1[i], iy1 = sy1[i], ix2 = sx2[i], iy2 = sy2[i];
      float a1 = sa[i];
      #pragma unroll 4
      for (int jj = 0; jj < 32; ++jj) {
        int j = jbase + jj;
        if (j < KTOP && j > i) {
          float jx1 = sx1[j], jy1 = sy1[j];       // j uniform -> LDS broadcast
          float jx2 = sx2[j], jy2 = sy2[j];
          float a2  = sa[j];
          float iw = fminf(ix2, jx2) - fmaxf(ix1, jx1);
          float ih = fminf(iy2, jy2) - fmaxf(iy1, jy1);
          float inter = fmaxf(iw, 0.0f) * fmaxf(ih, 0.0f);
          // iou > 0.65  <=>  inter > 0.65*(a1+a2-inter+1e-9)
          if (inter > 0.65f * (a1 + a2 - inter + 1e-9f)) bits |= (1u << jj);
        }
      }
    }
    gmask[((size_t)b * 16 + w) * 512 + i] = bits;   // [b][w][i], coalesced
  }
}

// ---------------- Kernel 5: greedy scan + final write (8 blocks) ----------
__global__ __launch_bounds__(256) void k_nms(
    const unsigned* __restrict__ gmask, const unsigned* __restrict__ invalg,
    const float* __restrict__ seldet, float* __restrict__ out)
{
  const int b = blockIdx.x;
  const int tid = threadIdx.x;
  const int lane = tid & 63;
  __shared__ unsigned sm[KTOP * 17];     // [i][w], stride 17 -> conflict-free
  __shared__ unsigned sh_keep[16];
  for (int g = tid; g < KTOP * 16; g += 256) {
    int w = g / KTOP, i = g - w * KTOP;
    sm[i * 17 + w] = gmask[((size_t)b * 16 + w) * 512 + i];
  }
  __syncthreads();
  if (tid < 64) {
    unsigned sup   = (lane < 16) ? invalg[b * 16 + lane] : 0u;
    unsigned keepw = 0u;
    unsigned cur = (unsigned)__builtin_amdgcn_readlane((int)sup, 0);
    unsigned mA = (lane < 16) ? sm[0 * 17 + lane] : 0u;
    unsigned mB = (lane < 16) ? sm[1 * 17 + lane] : 0u;
    for (int i = 0; i < KTOP; i += 2) {
      bool ok = ((cur >> (i & 31)) & 1u) == 0u;
      if (ok) {
        sup |= mA;
        if (lane == (i >> 5)) keepw |= (1u << (i & 31));
      }
      cur = (unsigned)__builtin_amdgcn_readlane((int)sup, (i + 1) >> 5);
      mA = (lane < 16 && (i + 2) < KTOP) ? sm[(i + 2) * 17 + lane] : 0u;
      bool ok2 = ((cur >> ((i + 1) & 31)) & 1u) == 0u;
      if (ok2) {
        sup |= mB;
        if (lane == ((i + 1) >> 5)) keepw |= (1u << ((i + 1) & 31));
      }
      cur = (unsigned)__builtin_amdgcn_readlane((int)sup, (i + 2) >> 5);
      mB = (lane < 16 && (i + 3) < KTOP) ? sm[(i + 3) * 17 + lane] : 0u;
    }
    if (lane < 16) sh_keep[lane] = keepw;
  }
  __syncthreads();
  for (int x = tid; x < KTOP * 7; x += 256) {
    int k = x / 7;
    float keepf = ((sh_keep[k >> 5] >> (k & 31)) & 1u) ? 1.0f : 0.0f;
    out[(size_t)b * (KTOP * 7) + x] = seldet[(size_t)b * (KTOP * 7) + x] * keepf;
  }
}

extern "C" void kernel_launch(void* const* d_in, const int* in_sizes, int n_in,
                              void* d_out, int out_size, void* d_ws, size_t ws_size,
                              hipStream_t stream) {
  const float* p8  = (const float*)d_in[0];
  const float* p16 = (const float*)d_in[1];
  const float* p32 = (const float*)d_in[2];
  float* out = (float*)d_out;
  // workspace layout (~1.3 MB — fits in one XCD L2)
  unsigned* hist2   = (unsigned*)d_ws;                          // [8][1024]
  unsigned* keys    = hist2 + (size_t)NIMG * NGRP;              // [8][NPI]
  unsigned* selanch = keys + (size_t)NIMG * NPI;                // [8][500]
  unsigned* invalg  = selanch + (size_t)NIMG * KTOP;            // [8][16]
  unsigned* gmask   = invalg + NIMG * 16;                       // [8][16][512]
  float*    seldet  = (float*)(gmask + (size_t)NIMG * 16 * 512);// [8][500*7]

  hipMemsetAsync(hist2, 0, (size_t)NIMG * NGRP * 4, stream);
  k_score <<<dim3(67, NIMG), 256, 0, stream>>>(p8, p16, p32, keys, hist2);
  k_select<<<dim3(NIMG), 1024, 0, stream>>>(hist2, keys, selanch, invalg);
  k_gather<<<dim3(8, NIMG), 256, 0, stream>>>(p8, p16, p32, selanch, seldet);
  k_iou   <<<dim3(16, NIMG), 256, 0, stream>>>(seldet, invalg, gmask);
  k_nms   <<<dim3(NIMG), 256, 0, stream>>>(gmask, invalg, seldet, out);
}